// Round 1
// baseline (702.259 us; speedup 1.0000x reference)
//
#include <hip/hip_runtime.h>

#define PWB 7
#define PHB 7
#define HDIM 48
#define WDIM 48
#define CDIM 256

// One wave (64 threads) per output bin (b, ph, pw).
// Lane t handles channels [4t, 4t+4) as a float4 -> 64 lanes x 16B = 1KB per
// vector load, perfectly coalesced along the innermost C dimension.
__global__ __launch_bounds__(64) void roi_pool_max_kernel(
    const float* __restrict__ fm,    // (B, 48, 48, 256)
    const float* __restrict__ rois,  // (B, 4)
    float* __restrict__ out)         // (B, 7, 7, 256)
{
    const int blk = blockIdx.x;
    const int pw  = blk % PWB;
    const int ph  = (blk / PWB) % PHB;
    const int b   = blk / (PWB * PHB);
    const int tid = threadIdx.x;

    // ROI -> integer box (truncation matches astype(int32) on positive floats)
    const float r0 = rois[b * 4 + 0];
    const float r1 = rois[b * 4 + 1];
    const float r2 = rois[b * 4 + 2];
    const float r3 = rois[b * 4 + 3];
    const int x0 = (int)(WDIM * r0);
    const int y0 = (int)(HDIM * r1);
    const int x1 = (int)(WDIM * r2);
    const int y1 = (int)(HDIM * r3);

    // Reference's _bin_ends: w = S // 7, k = 7 - w.
    // bin j < k: [j*w, (j+1)*w) ; bin j >= k: width w+1.
    // Valid region-relative coords additionally require r < S.
    const int Sy = y1 - y0;
    const int wy = Sy / PHB;
    const int ky = PHB - wy;
    int ys, ye;
    if (ph < ky) { ys = ph * wy; ye = ys + wy; }
    else         { ys = ky * wy + (ph - ky) * (wy + 1); ye = ys + wy + 1; }
    if (ye > Sy) ye = Sy;
    ys += y0; ye += y0;

    const int Sx = x1 - x0;
    const int wx = Sx / PWB;
    const int kx = PWB - wx;
    int xs, xe;
    if (pw < kx) { xs = pw * wx; xe = xs + wx; }
    else         { xs = kx * wx + (pw - kx) * (wx + 1); xe = xs + wx + 1; }
    if (xe > Sx) xe = Sx;
    xs += x0; xe += x0;

    // Running max over the bin's pixels (empty bin -> -inf, matching
    // jax segment_max identity; cannot occur for these ROI distributions).
    float4 m = make_float4(-INFINITY, -INFINITY, -INFINITY, -INFINITY);

    const float4* __restrict__ fmb =
        (const float4*)fm + (size_t)b * (HDIM * WDIM) * (CDIM / 4) + tid;
    for (int y = ys; y < ye; ++y) {
        const float4* __restrict__ row = fmb + (size_t)(y * WDIM) * (CDIM / 4);
        for (int x = xs; x < xe; ++x) {
            const float4 v = row[(size_t)x * (CDIM / 4)];
            m.x = fmaxf(m.x, v.x);
            m.y = fmaxf(m.y, v.y);
            m.z = fmaxf(m.z, v.z);
            m.w = fmaxf(m.w, v.w);
        }
    }

    float4* __restrict__ o = (float4*)out + (size_t)blk * (CDIM / 4) + tid;
    *o = m;
}

extern "C" void kernel_launch(void* const* d_in, const int* in_sizes, int n_in,
                              void* d_out, int out_size, void* d_ws, size_t ws_size,
                              hipStream_t stream) {
    const float* fm   = (const float*)d_in[0];
    const float* rois = (const float*)d_in[1];
    float* out = (float*)d_out;

    const int nblocks = 256 * PHB * PWB;  // B * 7 * 7 = 12544
    roi_pool_max_kernel<<<nblocks, 64, 0, stream>>>(fm, rois, out);
}